// Round 4
// baseline (245.678 us; speedup 1.0000x reference)
//
#include <hip/hip_runtime.h>

#define B_N 256
#define C_N 50000
#define D_N 512
#define ALPHA 0.5f

// Kernel A: ONE dispatch doing both independent streaming jobs concurrently:
//  - role copy (blockIdx%3 in {0,1}, 6250 blocks): newc row-copy from centers,
//    4 independent float4 loads -> 4 stores per thread (m13 6.3 TB/s pattern).
//  - role scan (blockIdx%3 == 2, 3125 blocks): scan onehot for the 1.0 per
//    row, write labels[b]. Interleaved roles keep both HBM streams in flight
//    for the whole dispatch instead of serializing two kernels.
__global__ __launch_bounds__(256) void fused_copy_scan(
        const float4* __restrict__ centers4, float4* __restrict__ newc4,
        const float4* __restrict__ onehot4, int* __restrict__ labels) {
    int t = threadIdx.x;
    int bid = blockIdx.x;
    int q = bid / 3;
    int r = bid - q * 3;
    if (r < 2) {
        // copy role: block id 0..6249 over 6.4M float4
        size_t base = (size_t)(q * 2 + r) * 1024 + t;
        float4 v0 = centers4[base];
        float4 v1 = centers4[base + 256];
        float4 v2 = centers4[base + 512];
        float4 v3 = centers4[base + 768];
        newc4[base]       = v0;
        newc4[base + 256] = v1;
        newc4[base + 512] = v2;
        newc4[base + 768] = v3;
    } else {
        // scan role: block id 0..3124 over 3.2M float4 of onehot
        int base = q * 1024 + t;
        float4 v[4];
#pragma unroll
        for (int k = 0; k < 4; ++k) v[k] = onehot4[base + k * 256];
#pragma unroll
        for (int k = 0; k < 4; ++k) {
            float4 f = v[k];
            if (f.x != 0.f || f.y != 0.f || f.z != 0.f || f.w != 0.f) {
                int g = (base + k * 256) * 4;
                float e[4] = {f.x, f.y, f.z, f.w};
#pragma unroll
                for (int j = 0; j < 4; ++j) {
                    if (e[j] != 0.f) {
                        int gg = g + j;
                        int b = gg / C_N;
                        int c = gg - b * C_N;
                        labels[b] = c;              // exactly one writer per b
                    }
                }
            }
        }
    }
}

// Kernel B: per-sample block b (256 blocks x 128 threads):
//  1) result[b] = ||x[b] - centers[label_b]||^2
//  2) if b is the canonical (first) sample of its class c, rewrite
//     newc[c] = centers[c]*(1-a*n/(n+1)) + (a/(n+1)) * sum_{label=c} x
// Runs after kernel A so the copy's write of row c is overwritten.
__global__ __launch_bounds__(128) void finalize(
        const float* __restrict__ x,
        const float* __restrict__ centers,
        const int* __restrict__ labels,
        float* __restrict__ result,
        float* __restrict__ newc) {
    __shared__ int sl[B_N];
    __shared__ float ws[2];
    int t = threadIdx.x;
    int b = blockIdx.x;
    sl[t] = labels[t];
    sl[t + 128] = labels[t + 128];
    __syncthreads();
    int c = sl[b];
    float4 xv = ((const float4*)(x + (size_t)b * D_N))[t];
    float4 cv = ((const float4*)(centers + (size_t)c * D_N))[t];

    // --- squared distance ---
    float dx = xv.x - cv.x, dy = xv.y - cv.y, dz = xv.z - cv.z, dw = xv.w - cv.w;
    float s = dx * dx + dy * dy + dz * dz + dw * dw;
#pragma unroll
    for (int off = 32; off > 0; off >>= 1) s += __shfl_down(s, off, 64);
    if ((t & 63) == 0) ws[t >> 6] = s;
    __syncthreads();
    if (t == 0) result[b] = ws[0] + ws[1];

    // --- canonical check + count (block-uniform scan of 256 LDS ints) ---
    int n = 0;
    bool canonical = true;
    for (int i = 0; i < B_N; ++i) {
        if (sl[i] == c) {
            n++;
            if (i < b) canonical = false;
        }
    }
    if (!canonical) return;

    float4 sx = make_float4(0.f, 0.f, 0.f, 0.f);
    for (int i = 0; i < B_N; ++i) {
        if (sl[i] == c) {                           // block-uniform branch
            float4 v = ((const float4*)(x + (size_t)i * D_N))[t];
            sx.x += v.x; sx.y += v.y; sx.z += v.z; sx.w += v.w;
        }
    }
    float inv = 1.0f / (float)(n + 1);
    float ac = 1.0f - ALPHA * (float)n * inv;
    float bc = ALPHA * inv;
    float4 res;
    res.x = cv.x * ac + sx.x * bc;
    res.y = cv.y * ac + sx.y * bc;
    res.z = cv.z * ac + sx.z * bc;
    res.w = cv.w * ac + sx.w * bc;
    ((float4*)(newc + (size_t)c * D_N))[t] = res;
}

extern "C" void kernel_launch(void* const* d_in, const int* in_sizes, int n_in,
                              void* d_out, int out_size, void* d_ws, size_t ws_size,
                              hipStream_t stream) {
    const float* x       = (const float*)d_in[0];   // [B, D]
    const float* onehot  = (const float*)d_in[1];   // [B, C]
    const float* centers = (const float*)d_in[2];   // [C, D]
    float* out    = (float*)d_out;
    float* result = out;                            // [B, 1] -> 256 floats
    float* newc   = out + B_N;                      // [C, D]

    int* labels = (int*)d_ws;                       // B ints (fully overwritten)

    // 6250 copy blocks + 3125 scan blocks, interleaved by blockIdx%3
    fused_copy_scan<<<9375, 256, 0, stream>>>(
        (const float4*)centers, (float4*)newc, (const float4*)onehot, labels);
    finalize<<<B_N, 128, 0, stream>>>(x, centers, labels, result, newc);
}

// Round 5
// 244.835 us; speedup vs baseline: 1.0034x; 1.0034x over previous
//
#include <hip/hip_runtime.h>

#define B_N 256
#define C_N 50000
#define D_N 512
#define ALPHA 0.5f

// Kernel 1: recover labels[b] from the one-hot rows. Pure-read streaming:
// 1250 blocks x 256 threads x 10 float4 = 3.2M float4 = 51.2 MB, exact cover.
// All 10 loads issued before any consumer -> 10 outstanding 16B loads/lane.
__global__ __launch_bounds__(256) void find_labels(
        const float4* __restrict__ onehot4, int* __restrict__ labels) {
    int t = threadIdx.x;
    int base = blockIdx.x * 2560 + t;                   // float4 index of k=0
    float4 v[10];
#pragma unroll
    for (int k = 0; k < 10; ++k) v[k] = onehot4[base + k * 256];
#pragma unroll
    for (int k = 0; k < 10; ++k) {
        float4 f = v[k];
        if (f.x != 0.f || f.y != 0.f || f.z != 0.f || f.w != 0.f) {
            int g = (base + k * 256) * 4;
            float e[4] = {f.x, f.y, f.z, f.w};
#pragma unroll
            for (int j = 0; j < 4; ++j) {
                if (e[j] != 0.f) {
                    int gg = g + j;
                    int b = gg / C_N;
                    int c = gg - b * C_N;
                    labels[b] = c;                      // exactly one writer per b
                }
            }
        }
    }
}

// Kernel 2: per-sample block b (256 blocks x 128 threads):
//  1) result[b] = ||x[b] - centers[label_b]||^2
//  2) if b is the canonical (first) sample of its class c, rewrite
//     newc[c] = centers[c]*(1-a*n/(n+1)) + (a/(n+1)) * sum_{label=c} x
// Runs after the D2D copy so the copied row c is overwritten.
__global__ __launch_bounds__(128) void finalize(
        const float* __restrict__ x,
        const float* __restrict__ centers,
        const int* __restrict__ labels,
        float* __restrict__ result,
        float* __restrict__ newc) {
    __shared__ int sl[B_N];
    __shared__ float ws[2];
    int t = threadIdx.x;
    int b = blockIdx.x;
    sl[t] = labels[t];
    sl[t + 128] = labels[t + 128];
    __syncthreads();
    int c = sl[b];
    float4 xv = ((const float4*)(x + (size_t)b * D_N))[t];
    float4 cv = ((const float4*)(centers + (size_t)c * D_N))[t];

    // --- squared distance ---
    float dx = xv.x - cv.x, dy = xv.y - cv.y, dz = xv.z - cv.z, dw = xv.w - cv.w;
    float s = dx * dx + dy * dy + dz * dz + dw * dw;
#pragma unroll
    for (int off = 32; off > 0; off >>= 1) s += __shfl_down(s, off, 64);
    if ((t & 63) == 0) ws[t >> 6] = s;
    __syncthreads();
    if (t == 0) result[b] = ws[0] + ws[1];

    // --- canonical check + count (block-uniform scan of 256 LDS ints) ---
    int n = 0;
    bool canonical = true;
    for (int i = 0; i < B_N; ++i) {
        if (sl[i] == c) {
            n++;
            if (i < b) canonical = false;
        }
    }
    if (!canonical) return;

    float4 sx = make_float4(0.f, 0.f, 0.f, 0.f);
    for (int i = 0; i < B_N; ++i) {
        if (sl[i] == c) {                           // block-uniform branch
            float4 v = ((const float4*)(x + (size_t)i * D_N))[t];
            sx.x += v.x; sx.y += v.y; sx.z += v.z; sx.w += v.w;
        }
    }
    float inv = 1.0f / (float)(n + 1);
    float ac = 1.0f - ALPHA * (float)n * inv;
    float bc = ALPHA * inv;
    float4 res;
    res.x = cv.x * ac + sx.x * bc;
    res.y = cv.y * ac + sx.y * bc;
    res.z = cv.z * ac + sx.z * bc;
    res.w = cv.w * ac + sx.w * bc;
    ((float4*)(newc + (size_t)c * D_N))[t] = res;
}

extern "C" void kernel_launch(void* const* d_in, const int* in_sizes, int n_in,
                              void* d_out, int out_size, void* d_ws, size_t ws_size,
                              hipStream_t stream) {
    const float* x       = (const float*)d_in[0];   // [B, D]
    const float* onehot  = (const float*)d_in[1];   // [B, C]
    const float* centers = (const float*)d_in[2];   // [C, D]
    float* out    = (float*)d_out;
    float* result = out;                            // [B, 1] -> 256 floats
    float* newc   = out + B_N;                      // [C, D]

    int* labels = (int*)d_ws;                       // B ints (fully overwritten)

    // bulk row copy via the runtime's tuned blit path (graph-capture safe)
    hipMemcpyAsync(newc, centers, (size_t)C_N * D_N * sizeof(float),
                   hipMemcpyDeviceToDevice, stream);
    find_labels<<<1250, 256, 0, stream>>>((const float4*)onehot, labels);
    finalize<<<B_N, 128, 0, stream>>>(x, centers, labels, result, newc);
}